// Round 1
// baseline (595.395 us; speedup 1.0000x reference)
//
#include <hip/hip_runtime.h>
#include <hip/hip_bf16.h>
#include <math.h>

#define DIM 1024
#define NTOK 2048   // B*L = 4*512
#define LSEQ 512
#define NB 4
#define DTR 64
#define DST 16

__device__ __forceinline__ float softplus_f(float x) {
    return (x > 20.f) ? x : log1pf(__expf(x));
}

// ---------------- LayerNorm: one block per row ----------------
__global__ __launch_bounds__(256) void ln_kernel(
    const float* __restrict__ x, const float* __restrict__ gamma,
    const float* __restrict__ beta, float* __restrict__ out) {
    const int row = blockIdx.x;
    const int tid = threadIdx.x;
    const float4* xr = (const float4*)(x + (size_t)row * DIM);
    float4 v = xr[tid];
    float s  = v.x + v.y + v.z + v.w;
    float sq = v.x*v.x + v.y*v.y + v.z*v.z + v.w*v.w;
    for (int o = 32; o > 0; o >>= 1) {
        s  += __shfl_down(s, o);
        sq += __shfl_down(sq, o);
    }
    __shared__ float red[8];
    if ((tid & 63) == 0) { red[tid >> 6] = s; red[4 + (tid >> 6)] = sq; }
    __syncthreads();
    float st  = red[0] + red[1] + red[2] + red[3];
    float sqt = red[4] + red[5] + red[6] + red[7];
    float mu = st * (1.f / DIM);
    float var = sqt * (1.f / DIM) - mu * mu;
    float rstd = rsqrtf(var + 1e-6f);
    float4 g = ((const float4*)gamma)[tid];
    float4 bt = ((const float4*)beta)[tid];
    float4 o4;
    o4.x = (v.x - mu) * rstd * g.x + bt.x;
    o4.y = (v.y - mu) * rstd * g.y + bt.y;
    o4.z = (v.z - mu) * rstd * g.z + bt.z;
    o4.w = (v.w - mu) * rstd * g.w + bt.w;
    ((float4*)(out + (size_t)row * DIM))[tid] = o4;
}

// ---------------- Tiled fp32 GEMM: C = act(A[M,K] @ W[K,N] + bias) ----------------
// ACT 0: C = v, C2 = silu(v).   ACT 1: C = softplus(v).
template<int ACT>
__global__ __launch_bounds__(256) void gemm_kernel(
    const float* __restrict__ A, const float* __restrict__ W,
    const float* __restrict__ bias, float* __restrict__ C, float* C2,
    int M, int N, int K) {
    __shared__ float As[16][68];
    __shared__ float Bs[16][68];
    const int tid = threadIdx.x;
    const int bm = blockIdx.y * 64;
    const int bn = blockIdx.x * 64;
    const int tm = (tid >> 4) * 4;   // 0..60
    const int tn = (tid & 15) * 4;   // 0..60
    const int ka = tid & 15, ma = tid >> 4;
    const int kb = tid >> 6, nb = tid & 63;
    float acc[4][4] = {};
    for (int k0 = 0; k0 < K; k0 += 16) {
        #pragma unroll
        for (int i = 0; i < 4; ++i)
            As[ka][ma + 16 * i] = A[(size_t)(bm + ma + 16 * i) * K + k0 + ka];
        #pragma unroll
        for (int i = 0; i < 4; ++i)
            Bs[kb + 4 * i][nb] = W[(size_t)(k0 + kb + 4 * i) * N + bn + nb];
        __syncthreads();
        #pragma unroll
        for (int k = 0; k < 16; ++k) {
            float a[4], b[4];
            #pragma unroll
            for (int i = 0; i < 4; ++i) a[i] = As[k][tm + i];
            #pragma unroll
            for (int i = 0; i < 4; ++i) b[i] = Bs[k][tn + i];
            #pragma unroll
            for (int mi = 0; mi < 4; ++mi)
                #pragma unroll
                for (int ni = 0; ni < 4; ++ni)
                    acc[mi][ni] = fmaf(a[mi], b[ni], acc[mi][ni]);
        }
        __syncthreads();
    }
    #pragma unroll
    for (int mi = 0; mi < 4; ++mi) {
        const int row = bm + tm + mi;
        #pragma unroll
        for (int ni = 0; ni < 4; ++ni) {
            const int col = bn + tn + ni;
            float v = acc[mi][ni] + bias[col];
            if (ACT == 0) {
                C[(size_t)row * N + col] = v;
                C2[(size_t)row * N + col] = v / (1.f + __expf(-v));  // silu
            } else {
                C[(size_t)row * N + col] = softplus_f(v);
            }
        }
    }
}

// ---------------- dbc = u @ W_x + b_x  (N=96, K=1024), 8 rows per block ----------------
__global__ __launch_bounds__(128) void dbc_kernel(
    const float* __restrict__ u1, const float* __restrict__ u2,
    const float* __restrict__ Wx1, const float* __restrict__ bx1,
    const float* __restrict__ Wx2, const float* __restrict__ bx2,
    float* __restrict__ dbc1, float* __restrict__ dbc2) {
    const int s = blockIdx.y;
    const float* __restrict__ u   = s ? u2   : u1;
    const float* __restrict__ Wx  = s ? Wx2  : Wx1;
    const float* __restrict__ bx  = s ? bx2  : bx1;
    float* __restrict__ dbc       = s ? dbc2 : dbc1;
    const int row0 = blockIdx.x * 8;
    const int j = threadIdx.x;
    if (j >= 96) return;
    float acc[8];
    const float bj = bx[j];
    #pragma unroll
    for (int r = 0; r < 8; ++r) acc[r] = bj;
    const float* ur = u + (size_t)row0 * DIM;
    for (int k = 0; k < DIM; k += 4) {
        float4 uv[8];
        #pragma unroll
        for (int r = 0; r < 8; ++r) uv[r] = *(const float4*)(ur + (size_t)r * DIM + k);
        #pragma unroll
        for (int kk = 0; kk < 4; ++kk) {
            float w = Wx[(size_t)(k + kk) * 96 + j];
            #pragma unroll
            for (int r = 0; r < 8; ++r) {
                float uvv = kk == 0 ? uv[r].x : kk == 1 ? uv[r].y : kk == 2 ? uv[r].z : uv[r].w;
                acc[r] = fmaf(uvv, w, acc[r]);
            }
        }
    }
    #pragma unroll
    for (int r = 0; r < 8; ++r) dbc[(size_t)(row0 + r) * 96 + j] = acc[r];
}

// ---------------- delta = softplus(dbc[:, :64] @ W_dt + b_dt)  (N=1024, K=64), 4 rows/block ----------------
__global__ __launch_bounds__(256) void delta_kernel(
    const float* __restrict__ dbc1, const float* __restrict__ dbc2,
    const float* __restrict__ Wdt1, const float* __restrict__ bdt1,
    const float* __restrict__ Wdt2, const float* __restrict__ bdt2,
    float* __restrict__ delta1, float* __restrict__ delta2) {
    const int s = blockIdx.y;
    const float* __restrict__ dbc = s ? dbc2 : dbc1;
    const float* __restrict__ Wdt = s ? Wdt2 : Wdt1;
    const float* __restrict__ bdt = s ? bdt2 : bdt1;
    float* __restrict__ delta     = s ? delta2 : delta1;
    const int row0 = blockIdx.x * 4;
    const int tid = threadIdx.x;
    __shared__ float rs[4][64];
    rs[tid >> 6][tid & 63] = dbc[(size_t)(row0 + (tid >> 6)) * 96 + (tid & 63)];
    __syncthreads();
    float acc[4][4];
    #pragma unroll
    for (int i = 0; i < 4; ++i) {
        float b = bdt[tid + 256 * i];
        #pragma unroll
        for (int r = 0; r < 4; ++r) acc[r][i] = b;
    }
    for (int k = 0; k < 64; ++k) {
        #pragma unroll
        for (int i = 0; i < 4; ++i) {
            float w = Wdt[(size_t)k * DIM + tid + 256 * i];
            #pragma unroll
            for (int r = 0; r < 4; ++r) acc[r][i] = fmaf(rs[r][k], w, acc[r][i]);
        }
    }
    #pragma unroll
    for (int r = 0; r < 4; ++r)
        #pragma unroll
        for (int i = 0; i < 4; ++i)
            delta[(size_t)(row0 + r) * DIM + tid + 256 * i] = softplus_f(acc[r][i]);
}

// ---------------- selective scan: thread = (b, d, n); 16-lane reduce over n ----------------
__global__ __launch_bounds__(256) void scan_kernel(
    const float* __restrict__ delta1, const float* __restrict__ u1c, const float* __restrict__ dbc1,
    const float* __restrict__ Alog1, const float* __restrict__ D1p, float* __restrict__ y1,
    const float* __restrict__ delta2, const float* __restrict__ u2c, const float* __restrict__ dbc2,
    const float* __restrict__ Alog2, const float* __restrict__ D2p, float* __restrict__ y2) {
    const int s = blockIdx.z;
    const float* __restrict__ delta = s ? delta2 : delta1;
    const float* __restrict__ u     = s ? u2c   : u1c;
    const float* __restrict__ dbc   = s ? dbc2  : dbc1;
    const float* __restrict__ Alog  = s ? Alog2 : Alog1;
    const float* __restrict__ Dp    = s ? D2p   : D1p;
    float* __restrict__ y           = s ? y2    : y1;
    const int tid = threadIdx.x;
    const int n = tid & 15;
    const int d = blockIdx.x * 16 + (tid >> 4);
    const int b = blockIdx.y;
    const float a = -__expf(Alog[d * DST + n]);
    const float dcf = Dp[d];
    const size_t rowbase = (size_t)b * LSEQ;
    float h = 0.f;
    float dl = delta[rowbase * DIM + d];
    float uu = u[rowbase * DIM + d];
    float Bn = dbc[rowbase * 96 + DTR + n];
    float Cn = dbc[rowbase * 96 + DTR + DST + n];
    for (int l = 0; l < LSEQ; ++l) {
        const float dl_c = dl, uu_c = uu, Bn_c = Bn, Cn_c = Cn;
        if (l + 1 < LSEQ) {
            const size_t r2 = rowbase + l + 1;
            dl = delta[r2 * DIM + d];
            uu = u[r2 * DIM + d];
            Bn = dbc[r2 * 96 + DTR + n];
            Cn = dbc[r2 * 96 + DTR + DST + n];
        }
        const float dA = __expf(dl_c * a);
        h = fmaf(dA, h, dl_c * Bn_c * uu_c);
        float p = h * Cn_c;
        p += __shfl_xor(p, 1);
        p += __shfl_xor(p, 2);
        p += __shfl_xor(p, 4);
        p += __shfl_xor(p, 8);
        if (n == 0) y[(rowbase + l) * DIM + d] = fmaf(uu_c, dcf, p);
    }
}

// ---------------- out = (y1 + y2) * z + skip  (z lives in d_out) ----------------
__global__ __launch_bounds__(256) void final_kernel(
    const float* __restrict__ y1, const float* __restrict__ y2,
    const float* __restrict__ skip, float* io) {
    const int i = blockIdx.x * 256 + threadIdx.x;
    float4 a = ((const float4*)y1)[i];
    float4 b = ((const float4*)y2)[i];
    float4 sk = ((const float4*)skip)[i];
    float4 z = ((float4*)io)[i];
    float4 o;
    o.x = (a.x + b.x) * z.x + sk.x;
    o.y = (a.y + b.y) * z.y + sk.y;
    o.z = (a.z + b.z) * z.z + sk.z;
    o.w = (a.w + b.w) * z.w + sk.w;
    ((float4*)io)[i] = o;
}

extern "C" void kernel_launch(void* const* d_in, const int* in_sizes, int n_in,
                              void* d_out, int out_size, void* d_ws, size_t ws_size,
                              hipStream_t stream) {
    const float* inputs = (const float*)d_in[0];
    const float* gamma  = (const float*)d_in[1];
    const float* beta   = (const float*)d_in[2];
    const float* W_proj = (const float*)d_in[3];
    const float* b_proj = (const float*)d_in[4];
    const float* W_fc   = (const float*)d_in[5];
    const float* b_fc   = (const float*)d_in[6];
    const float* W_bc   = (const float*)d_in[7];
    const float* b_bc   = (const float*)d_in[8];
    const float* W_x1   = (const float*)d_in[9];
    const float* b_x1   = (const float*)d_in[10];
    const float* W_dt1  = (const float*)d_in[11];
    const float* b_dt1  = (const float*)d_in[12];
    const float* A_log1 = (const float*)d_in[13];
    const float* D1     = (const float*)d_in[14];
    const float* W_x2   = (const float*)d_in[15];
    const float* b_x2   = (const float*)d_in[16];
    const float* W_dt2  = (const float*)d_in[17];
    const float* b_dt2  = (const float*)d_in[18];
    const float* A_log2 = (const float*)d_in[19];
    const float* D2     = (const float*)d_in[20];
    float* out = (float*)d_out;
    float* ws  = (float*)d_ws;

    const size_t NE = (size_t)NTOK * DIM;   // 2M floats
    float* xln    = ws;               // bufA: xln, later y1
    float* proj   = ws + NE;          // bufB: proj, later delta1
    float* u1     = ws + 2 * NE;
    float* u2     = ws + 3 * NE;
    float* delta2 = ws + 4 * NE;
    float* y2     = ws + 5 * NE;
    float* dbc1   = ws + 6 * NE;
    float* dbc2   = dbc1 + (size_t)NTOK * 96;
    float* y1     = xln;
    float* delta1 = proj;
    float* zbuf   = out;              // z = silu(proj) staged in d_out

    ln_kernel<<<NTOK, 256, 0, stream>>>(inputs, gamma, beta, xln);
    gemm_kernel<0><<<dim3(16, 32), 256, 0, stream>>>(xln, W_proj, b_proj, proj, zbuf, NTOK, DIM, DIM);
    gemm_kernel<1><<<dim3(16, 32), 256, 0, stream>>>(proj, W_fc, b_fc, u1, nullptr, NTOK, DIM, DIM);
    gemm_kernel<1><<<dim3(16, 32), 256, 0, stream>>>(proj, W_bc, b_bc, u2, nullptr, NTOK, DIM, DIM);
    dbc_kernel<<<dim3(NTOK / 8, 2), 128, 0, stream>>>(u1, u2, W_x1, b_x1, W_x2, b_x2, dbc1, dbc2);
    delta_kernel<<<dim3(NTOK / 4, 2), 256, 0, stream>>>(dbc1, dbc2, W_dt1, b_dt1, W_dt2, b_dt2, delta1, delta2);
    scan_kernel<<<dim3(DIM / 16, NB, 2), 256, 0, stream>>>(delta1, u1, dbc1, A_log1, D1, y1,
                                                           delta2, u2, dbc2, A_log2, D2, y2);
    final_kernel<<<NE / 4 / 256, 256, 0, stream>>>(y1, y2, inputs, out);
}

// Round 2
// 405.730 us; speedup vs baseline: 1.4675x; 1.4675x over previous
//
#include <hip/hip_runtime.h>
#include <hip/hip_bf16.h>
#include <math.h>

#define DIM 1024
#define NTOK 2048   // B*L = 4*512
#define LSEQ 512
#define NB 4
#define DTR 64
#define DST 16

typedef unsigned short ushort_t;
typedef __attribute__((ext_vector_type(8))) short bf16x8;
typedef __attribute__((ext_vector_type(4))) float f32x4;

__device__ __forceinline__ float softplus_f(float x) {
    return (x > 20.f) ? x : log1pf(__expf(x));
}
__device__ __forceinline__ ushort_t to_bf16_bits(float f) {
    __hip_bfloat16 h = __float2bfloat16(f);
    return *(ushort_t*)&h;
}
__device__ __forceinline__ float bf16_bits_to_f(ushort_t b) {
    return __uint_as_float(((unsigned int)b) << 16);
}

// ---------------- weight transpose + bf16 convert: Wt[n][k] = bf16(W[k][n]) ----------------
__global__ __launch_bounds__(256) void wconv_kernel(
    const float* __restrict__ W0, const float* __restrict__ W1, const float* __restrict__ W2,
    ushort_t* __restrict__ T0, ushort_t* __restrict__ T1, ushort_t* __restrict__ T2) {
    const float* W = blockIdx.z == 0 ? W0 : blockIdx.z == 1 ? W1 : W2;
    ushort_t* T    = blockIdx.z == 0 ? T0 : blockIdx.z == 1 ? T1 : T2;
    __shared__ float tile[64][65];
    const int k0 = blockIdx.x * 64, n0 = blockIdx.y * 64;
    const int tid = threadIdx.x;
    #pragma unroll
    for (int p = 0; p < 16; ++p) {
        int idx = p * 256 + tid;
        int i = idx >> 6, j = idx & 63;
        tile[i][j] = W[(size_t)(k0 + i) * DIM + n0 + j];
    }
    __syncthreads();
    #pragma unroll
    for (int p = 0; p < 16; ++p) {
        int idx = p * 256 + tid;
        int j = idx >> 6, i = idx & 63;
        T[(size_t)(n0 + j) * DIM + k0 + i] = to_bf16_bits(tile[i][j]);
    }
}

// ---------------- LayerNorm -> bf16 ----------------
__global__ __launch_bounds__(256) void ln_kernel(
    const float* __restrict__ x, const float* __restrict__ gamma,
    const float* __restrict__ beta, ushort_t* __restrict__ out) {
    const int row = blockIdx.x;
    const int tid = threadIdx.x;
    const float4* xr = (const float4*)(x + (size_t)row * DIM);
    float4 v = xr[tid];
    float s  = v.x + v.y + v.z + v.w;
    float sq = v.x*v.x + v.y*v.y + v.z*v.z + v.w*v.w;
    for (int o = 32; o > 0; o >>= 1) {
        s  += __shfl_down(s, o);
        sq += __shfl_down(sq, o);
    }
    __shared__ float red[8];
    if ((tid & 63) == 0) { red[tid >> 6] = s; red[4 + (tid >> 6)] = sq; }
    __syncthreads();
    float st  = red[0] + red[1] + red[2] + red[3];
    float sqt = red[4] + red[5] + red[6] + red[7];
    float mu = st * (1.f / DIM);
    float var = sqt * (1.f / DIM) - mu * mu;
    float rstd = rsqrtf(var + 1e-6f);
    float4 g = ((const float4*)gamma)[tid];
    float4 bt = ((const float4*)beta)[tid];
    ushort4 ob;
    ob.x = to_bf16_bits((v.x - mu) * rstd * g.x + bt.x);
    ob.y = to_bf16_bits((v.y - mu) * rstd * g.y + bt.y);
    ob.z = to_bf16_bits((v.z - mu) * rstd * g.z + bt.z);
    ob.w = to_bf16_bits((v.w - mu) * rstd * g.w + bt.w);
    ((ushort4*)(out + (size_t)row * DIM))[tid] = ob;
}

// ---------------- bf16 MFMA GEMM: act(A[M,K] @ Wt[N,K]^T + bias) ----------------
// BM=128, BN=64, BK=64; 4 waves in 2x2; wave tile 64x32 = 4x2 frags of 16x16.
// LDS linear [row][k8slot*8] with k8slot = k8 ^ (row&7) (pre-swizzled global source,
// same XOR on read -> rule #21 both-sides).
// ACT 0: outb = bf16(v), outf = silu(v).  ACT 1: outf = softplus(v).
template<int ACT>
__global__ __launch_bounds__(256) void mfma_gemm(
    const ushort_t* __restrict__ A, const ushort_t* __restrict__ Bt,
    const float* __restrict__ bias, ushort_t* __restrict__ outb, float* __restrict__ outf) {
    __shared__ __align__(16) ushort_t Asl[128 * 64];
    __shared__ __align__(16) ushort_t Bsl[64 * 64];
    const int tid = threadIdx.x;
    const int bm = blockIdx.y * 128;
    const int bn = blockIdx.x * 64;
    const int lane = tid & 63;
    const int wid = tid >> 6;
    const int r  = lane & 15;
    const int kg = lane >> 4;            // 0..3
    const int wm = wid >> 1, wn = wid & 1;

    f32x4 acc[4][2] = {};

    for (int k0 = 0; k0 < DIM; k0 += 64) {
        // stage A tile [128][64]: 1024 chunks of 16B
        #pragma unroll
        for (int q = 0; q < 4; ++q) {
            int c = q * 256 + tid;
            int mrow = c >> 3;
            int ksl = ((c & 7) ^ (mrow & 7)) << 3;
            __builtin_amdgcn_global_load_lds(
                (const __attribute__((address_space(1))) void*)(A + (size_t)(bm + mrow) * DIM + k0 + ksl),
                (__attribute__((address_space(3))) void*)(Asl + (size_t)c * 8), 16, 0, 0);
        }
        // stage B tile [64][64]: 512 chunks
        #pragma unroll
        for (int q = 0; q < 2; ++q) {
            int c = q * 256 + tid;
            int nrow = c >> 3;
            int ksl = ((c & 7) ^ (nrow & 7)) << 3;
            __builtin_amdgcn_global_load_lds(
                (const __attribute__((address_space(1))) void*)(Bt + (size_t)(bn + nrow) * DIM + k0 + ksl),
                (__attribute__((address_space(3))) void*)(Bsl + (size_t)c * 8), 16, 0, 0);
        }
        __syncthreads();   // compiler drains vmcnt before barrier
        #pragma unroll
        for (int kk = 0; kk < 2; ++kk) {
            const int sw = ((kk * 4 + kg) ^ (r & 7)) << 3;
            bf16x8 af[4], bfr[2];
            #pragma unroll
            for (int mi = 0; mi < 4; ++mi)
                af[mi] = *(const bf16x8*)&Asl[(wm * 64 + mi * 16 + r) * 64 + sw];
            #pragma unroll
            for (int nj = 0; nj < 2; ++nj)
                bfr[nj] = *(const bf16x8*)&Bsl[(wn * 32 + nj * 16 + r) * 64 + sw];
            #pragma unroll
            for (int mi = 0; mi < 4; ++mi)
                #pragma unroll
                for (int nj = 0; nj < 2; ++nj)
                    acc[mi][nj] = __builtin_amdgcn_mfma_f32_16x16x32_bf16(af[mi], bfr[nj], acc[mi][nj], 0, 0, 0);
        }
        __syncthreads();
    }

    // epilogue: row = bm + wm*64 + mi*16 + kg*4 + j, col = bn + wn*32 + nj*16 + r
    #pragma unroll
    for (int nj = 0; nj < 2; ++nj) {
        const int col = bn + wn * 32 + nj * 16 + r;
        const float bv = bias[col];
        #pragma unroll
        for (int mi = 0; mi < 4; ++mi) {
            const int rowb = bm + wm * 64 + mi * 16 + kg * 4;
            #pragma unroll
            for (int j = 0; j < 4; ++j) {
                float v = acc[mi][nj][j] + bv;
                size_t idx = (size_t)(rowb + j) * DIM + col;
                if (ACT == 0) {
                    outb[idx] = to_bf16_bits(v);
                    outf[idx] = v / (1.f + __expf(-v));   // silu
                } else {
                    outf[idx] = softplus_f(v);
                }
            }
        }
    }
}

// ---------------- dbc = u @ W_x + b_x  (N=96, K=1024), 8 rows per block ----------------
__global__ __launch_bounds__(128) void dbc_kernel(
    const float* __restrict__ u1, const float* __restrict__ u2,
    const float* __restrict__ Wx1, const float* __restrict__ bx1,
    const float* __restrict__ Wx2, const float* __restrict__ bx2,
    float* __restrict__ dbc1, float* __restrict__ dbc2) {
    const int s = blockIdx.y;
    const float* __restrict__ u   = s ? u2   : u1;
    const float* __restrict__ Wx  = s ? Wx2  : Wx1;
    const float* __restrict__ bx  = s ? bx2  : bx1;
    float* __restrict__ dbc       = s ? dbc2 : dbc1;
    const int row0 = blockIdx.x * 8;
    const int j = threadIdx.x;
    if (j >= 96) return;
    float acc[8];
    const float bj = bx[j];
    #pragma unroll
    for (int r = 0; r < 8; ++r) acc[r] = bj;
    const float* ur = u + (size_t)row0 * DIM;
    for (int k = 0; k < DIM; k += 4) {
        float4 uv[8];
        #pragma unroll
        for (int r = 0; r < 8; ++r) uv[r] = *(const float4*)(ur + (size_t)r * DIM + k);
        #pragma unroll
        for (int kk = 0; kk < 4; ++kk) {
            float w = Wx[(size_t)(k + kk) * 96 + j];
            #pragma unroll
            for (int r = 0; r < 8; ++r) {
                float uvv = kk == 0 ? uv[r].x : kk == 1 ? uv[r].y : kk == 2 ? uv[r].z : uv[r].w;
                acc[r] = fmaf(uvv, w, acc[r]);
            }
        }
    }
    #pragma unroll
    for (int r = 0; r < 8; ++r) dbc[(size_t)(row0 + r) * 96 + j] = acc[r];
}

// ---------------- delta = softplus(dbc[:, :64] @ W_dt + b_dt) -> bf16 ----------------
__global__ __launch_bounds__(256) void delta_kernel(
    const float* __restrict__ dbc1, const float* __restrict__ dbc2,
    const float* __restrict__ Wdt1, const float* __restrict__ bdt1,
    const float* __restrict__ Wdt2, const float* __restrict__ bdt2,
    ushort_t* __restrict__ delta1, ushort_t* __restrict__ delta2) {
    const int s = blockIdx.y;
    const float* __restrict__ dbc = s ? dbc2 : dbc1;
    const float* __restrict__ Wdt = s ? Wdt2 : Wdt1;
    const float* __restrict__ bdt = s ? bdt2 : bdt1;
    ushort_t* __restrict__ delta  = s ? delta2 : delta1;
    const int row0 = blockIdx.x * 4;
    const int tid = threadIdx.x;
    __shared__ float rs[4][64];
    rs[tid >> 6][tid & 63] = dbc[(size_t)(row0 + (tid >> 6)) * 96 + (tid & 63)];
    __syncthreads();
    float acc[4][4];
    #pragma unroll
    for (int i = 0; i < 4; ++i) {
        float b = bdt[tid + 256 * i];
        #pragma unroll
        for (int r = 0; r < 4; ++r) acc[r][i] = b;
    }
    for (int k = 0; k < 64; ++k) {
        #pragma unroll
        for (int i = 0; i < 4; ++i) {
            float w = Wdt[(size_t)k * DIM + tid + 256 * i];
            #pragma unroll
            for (int r = 0; r < 4; ++r) acc[r][i] = fmaf(rs[r][k], w, acc[r][i]);
        }
    }
    #pragma unroll
    for (int r = 0; r < 4; ++r)
        #pragma unroll
        for (int i = 0; i < 4; ++i)
            delta[(size_t)(row0 + r) * DIM + tid + 256 * i] = to_bf16_bits(softplus_f(acc[r][i]));
}

// ---------------- selective scan: thread=(b,d,n); 8-step chunks, dbuf register prefetch ----------------
#define CH 8
#define LOADC(S, base) do { \
    _Pragma("unroll") for (int j_ = 0; j_ < CH; ++j_) { \
        const size_t rr_ = rowbase + (base) + j_; \
        dl##S[j_] = bf16_bits_to_f(delta[rr_ * DIM + d]); \
        uu##S[j_] = u[rr_ * DIM + d]; \
        Bn##S[j_] = dbc[rr_ * 96 + DTR + n]; \
        Cn##S[j_] = dbc[rr_ * 96 + DTR + DST + n]; \
    } \
} while (0)

#define COMPUTE(S, base) do { \
    float e_[CH], dbu_[CH]; \
    _Pragma("unroll") for (int j_ = 0; j_ < CH; ++j_) { \
        e_[j_]   = __expf(dl##S[j_] * a); \
        dbu_[j_] = dl##S[j_] * Bn##S[j_] * uu##S[j_]; \
    } \
    _Pragma("unroll") for (int j_ = 0; j_ < CH; ++j_) { \
        h = fmaf(e_[j_], h, dbu_[j_]); \
        float p_ = h * Cn##S[j_]; \
        p_ += __shfl_xor(p_, 1); \
        p_ += __shfl_xor(p_, 2); \
        p_ += __shfl_xor(p_, 4); \
        p_ += __shfl_xor(p_, 8); \
        if (n == 0) y[(rowbase + (base) + j_) * DIM + d] = fmaf(uu##S[j_], dcf, p_); \
    } \
} while (0)

__global__ __launch_bounds__(256) void scan_kernel(
    const ushort_t* __restrict__ delta1, const float* __restrict__ u1c, const float* __restrict__ dbc1,
    const float* __restrict__ Alog1, const float* __restrict__ D1p, float* __restrict__ y1,
    const ushort_t* __restrict__ delta2, const float* __restrict__ u2c, const float* __restrict__ dbc2,
    const float* __restrict__ Alog2, const float* __restrict__ D2p, float* __restrict__ y2) {
    const int s = blockIdx.z;
    const ushort_t* __restrict__ delta = s ? delta2 : delta1;
    const float* __restrict__ u     = s ? u2c   : u1c;
    const float* __restrict__ dbc   = s ? dbc2  : dbc1;
    const float* __restrict__ Alog  = s ? Alog2 : Alog1;
    const float* __restrict__ Dp    = s ? D2p   : D1p;
    float* __restrict__ y           = s ? y2    : y1;
    const int tid = threadIdx.x;
    const int n = tid & 15;
    const int d = blockIdx.x * 16 + (tid >> 4);
    const int b = blockIdx.y;
    const float a = -__expf(Alog[d * DST + n]);
    const float dcf = Dp[d];
    const size_t rowbase = (size_t)b * LSEQ;
    float h = 0.f;
    float dlA[CH], uuA[CH], BnA[CH], CnA[CH];
    float dlB[CH], uuB[CH], BnB[CH], CnB[CH];
    LOADC(A, 0);
    for (int c = 0; c < LSEQ; c += 2 * CH) {
        LOADC(B, c + CH);
        COMPUTE(A, c);
        if (c + 2 * CH < LSEQ) LOADC(A, c + 2 * CH);
        COMPUTE(B, c + CH);
    }
}

// ---------------- out = (y1 + y2) * z + skip  (z lives in d_out) ----------------
__global__ __launch_bounds__(256) void final_kernel(
    const float* __restrict__ y1, const float* __restrict__ y2,
    const float* __restrict__ skip, float* io) {
    const int i = blockIdx.x * 256 + threadIdx.x;
    float4 a = ((const float4*)y1)[i];
    float4 b = ((const float4*)y2)[i];
    float4 sk = ((const float4*)skip)[i];
    float4 z = ((float4*)io)[i];
    float4 o;
    o.x = (a.x + b.x) * z.x + sk.x;
    o.y = (a.y + b.y) * z.y + sk.y;
    o.z = (a.z + b.z) * z.z + sk.z;
    o.w = (a.w + b.w) * z.w + sk.w;
    ((float4*)io)[i] = o;
}

extern "C" void kernel_launch(void* const* d_in, const int* in_sizes, int n_in,
                              void* d_out, int out_size, void* d_ws, size_t ws_size,
                              hipStream_t stream) {
    const float* inputs = (const float*)d_in[0];
    const float* gamma  = (const float*)d_in[1];
    const float* beta   = (const float*)d_in[2];
    const float* W_proj = (const float*)d_in[3];
    const float* b_proj = (const float*)d_in[4];
    const float* W_fc   = (const float*)d_in[5];
    const float* b_fc   = (const float*)d_in[6];
    const float* W_bc   = (const float*)d_in[7];
    const float* b_bc   = (const float*)d_in[8];
    const float* W_x1   = (const float*)d_in[9];
    const float* b_x1   = (const float*)d_in[10];
    const float* W_dt1  = (const float*)d_in[11];
    const float* b_dt1  = (const float*)d_in[12];
    const float* A_log1 = (const float*)d_in[13];
    const float* D1     = (const float*)d_in[14];
    const float* W_x2   = (const float*)d_in[15];
    const float* b_x2   = (const float*)d_in[16];
    const float* W_dt2  = (const float*)d_in[17];
    const float* b_dt2  = (const float*)d_in[18];
    const float* A_log2 = (const float*)d_in[19];
    const float* D2     = (const float*)d_in[20];
    float* out = (float*)d_out;
    char* wsb  = (char*)d_ws;

    // workspace layout (47.5 MB total):
    ushort_t* xln_bf  = (ushort_t*)wsb;                          // 4MB
    ushort_t* proj_bf = (ushort_t*)(wsb + (4u << 20));           // 4MB
    float*    y1      = (float*)wsb;                             // 8MB, overlays xln/proj (dead by scan)
    float*    u1      = (float*)(wsb + (8u << 20));              // 8MB
    float*    u2      = (float*)(wsb + (16u << 20));             // 8MB
    float*    y2      = (float*)(wsb + (24u << 20));             // 8MB
    ushort_t* delta1  = (ushort_t*)(wsb + (32u << 20));          // 4MB
    ushort_t* delta2  = (ushort_t*)(wsb + (36u << 20));          // 4MB
    ushort_t* WtP     = (ushort_t*)(wsb + (40u << 20));          // 2MB
    ushort_t* WtF     = (ushort_t*)(wsb + (42u << 20));          // 2MB
    ushort_t* WtB     = (ushort_t*)(wsb + (44u << 20));          // 2MB
    float*    dbc1    = (float*)(wsb + (46u << 20));             // 0.75MB
    float*    dbc2    = dbc1 + (size_t)NTOK * 96;                // 0.75MB
    float*    zbuf    = out;                                     // z = silu(proj) staged in d_out

    wconv_kernel<<<dim3(16, 16, 3), 256, 0, stream>>>(W_proj, W_fc, W_bc, WtP, WtF, WtB);
    ln_kernel<<<NTOK, 256, 0, stream>>>(inputs, gamma, beta, xln_bf);
    mfma_gemm<0><<<dim3(DIM / 64, NTOK / 128), 256, 0, stream>>>(xln_bf, WtP, b_proj, proj_bf, zbuf);
    mfma_gemm<1><<<dim3(DIM / 64, NTOK / 128), 256, 0, stream>>>(proj_bf, WtF, b_fc, nullptr, u1);
    mfma_gemm<1><<<dim3(DIM / 64, NTOK / 128), 256, 0, stream>>>(proj_bf, WtB, b_bc, nullptr, u2);
    dbc_kernel<<<dim3(NTOK / 8, 2), 128, 0, stream>>>(u1, u2, W_x1, b_x1, W_x2, b_x2, dbc1, dbc2);
    delta_kernel<<<dim3(NTOK / 4, 2), 256, 0, stream>>>(dbc1, dbc2, W_dt1, b_dt1, W_dt2, b_dt2, delta1, delta2);
    scan_kernel<<<dim3(DIM / 16, NB, 2), 256, 0, stream>>>(delta1, u1, dbc1, A_log1, D1, y1,
                                                           delta2, u2, dbc2, A_log2, D2, y2);
    final_kernel<<<(size_t)NTOK * DIM / 4 / 256, 256, 0, stream>>>(y1, y2, inputs, out);
}

// Round 4
// 337.988 us; speedup vs baseline: 1.7616x; 1.2004x over previous
//
#include <hip/hip_runtime.h>
#include <hip/hip_bf16.h>
#include <math.h>

#define DIM 1024
#define NTOK 2048   // B*L = 4*512
#define LSEQ 512
#define NB 4
#define DTR 64
#define DST 16
#define NCH 8
#define TCH 64      // LSEQ / NCH

typedef unsigned short ushort_t;
typedef __attribute__((ext_vector_type(8))) short bf16x8;
typedef __attribute__((ext_vector_type(4))) float f32x4;

__device__ __forceinline__ float softplus_f(float x) {
    return (x > 20.f) ? x : log1pf(__expf(x));
}
__device__ __forceinline__ ushort_t to_bf16_bits(float f) {
    __hip_bfloat16 h = __float2bfloat16(f);
    return *(ushort_t*)&h;
}
__device__ __forceinline__ float bf16_bits_to_f(ushort_t b) {
    return __uint_as_float(((unsigned int)b) << 16);
}
// x + dpp_perm(x); ctrl: 0xB1=quad xor1, 0x4E=quad xor2, 0x124=row_ror:4, 0x128=row_ror:8
template<int CTRL>
__device__ __forceinline__ float dpp_add(float x) {
    int xi = __float_as_int(x);
    int yi = __builtin_amdgcn_update_dpp(xi, xi, CTRL, 0xF, 0xF, false);
    return x + __int_as_float(yi);
}

// ---------------- weight transpose + bf16 convert: Wt[n][k] = bf16(W[k][n]) ----------------
__global__ __launch_bounds__(256) void wconv_kernel(
    const float* __restrict__ W0, const float* __restrict__ W1, const float* __restrict__ W2,
    ushort_t* __restrict__ T0, ushort_t* __restrict__ T1, ushort_t* __restrict__ T2) {
    const float* W = blockIdx.z == 0 ? W0 : blockIdx.z == 1 ? W1 : W2;
    ushort_t* T    = blockIdx.z == 0 ? T0 : blockIdx.z == 1 ? T1 : T2;
    __shared__ float tile[64][65];
    const int k0 = blockIdx.x * 64, n0 = blockIdx.y * 64;
    const int tid = threadIdx.x;
    #pragma unroll
    for (int p = 0; p < 16; ++p) {
        int idx = p * 256 + tid;
        int i = idx >> 6, j = idx & 63;
        tile[i][j] = W[(size_t)(k0 + i) * DIM + n0 + j];
    }
    __syncthreads();
    #pragma unroll
    for (int p = 0; p < 16; ++p) {
        int idx = p * 256 + tid;
        int j = idx >> 6, i = idx & 63;
        T[(size_t)(n0 + j) * DIM + k0 + i] = to_bf16_bits(tile[i][j]);
    }
}

// ---------------- LayerNorm -> bf16 ----------------
__global__ __launch_bounds__(256) void ln_kernel(
    const float* __restrict__ x, const float* __restrict__ gamma,
    const float* __restrict__ beta, ushort_t* __restrict__ out) {
    const int row = blockIdx.x;
    const int tid = threadIdx.x;
    const float4* xr = (const float4*)(x + (size_t)row * DIM);
    float4 v = xr[tid];
    float s  = v.x + v.y + v.z + v.w;
    float sq = v.x*v.x + v.y*v.y + v.z*v.z + v.w*v.w;
    for (int o = 32; o > 0; o >>= 1) {
        s  += __shfl_down(s, o);
        sq += __shfl_down(sq, o);
    }
    __shared__ float red[8];
    if ((tid & 63) == 0) { red[tid >> 6] = s; red[4 + (tid >> 6)] = sq; }
    __syncthreads();
    float st  = red[0] + red[1] + red[2] + red[3];
    float sqt = red[4] + red[5] + red[6] + red[7];
    float mu = st * (1.f / DIM);
    float var = sqt * (1.f / DIM) - mu * mu;
    float rstd = rsqrtf(var + 1e-6f);
    float4 g = ((const float4*)gamma)[tid];
    float4 bt = ((const float4*)beta)[tid];
    ushort4 ob;
    ob.x = to_bf16_bits((v.x - mu) * rstd * g.x + bt.x);
    ob.y = to_bf16_bits((v.y - mu) * rstd * g.y + bt.y);
    ob.z = to_bf16_bits((v.z - mu) * rstd * g.z + bt.z);
    ob.w = to_bf16_bits((v.w - mu) * rstd * g.w + bt.w);
    ((ushort4*)(out + (size_t)row * DIM))[tid] = ob;
}

// ---------------- bf16 MFMA GEMM, 64x64 tile, BK=64, double-buffered LDS ----------------
// 4 waves in 2x2; wave tile 32x32 = 2x2 frags of 16x16.
// LDS [row][k8slot*8], k8slot = k8 ^ (row&7); pre-swizzled global source (rule #21).
// ACT 0: outb = bf16(v), outf = silu(v).  ACT 1: outf = softplus(v).
template<int ACT>
__global__ __launch_bounds__(256) void mfma_gemm(
    const ushort_t* __restrict__ A, const ushort_t* __restrict__ Bt,
    const float* __restrict__ bias, ushort_t* __restrict__ outb, float* __restrict__ outf) {
    __shared__ __align__(16) ushort_t Asl[2][64 * 64];
    __shared__ __align__(16) ushort_t Bsl[2][64 * 64];
    const int tid = threadIdx.x;
    const int bm = blockIdx.y * 64;
    const int bn = blockIdx.x * 64;
    const int lane = tid & 63;
    const int wid = tid >> 6;
    const int r  = lane & 15;
    const int kg = lane >> 4;            // 0..3
    const int wm = wid >> 1, wn = wid & 1;

    f32x4 acc[2][2] = {};

    auto STAGE = [&](int buf, int k0) {
        #pragma unroll
        for (int q = 0; q < 2; ++q) {
            int c = q * 256 + tid;
            int row = c >> 3;
            int ksl = ((c & 7) ^ (row & 7)) << 3;
            __builtin_amdgcn_global_load_lds(
                (const __attribute__((address_space(1))) void*)(A + (size_t)(bm + row) * DIM + k0 + ksl),
                (__attribute__((address_space(3))) void*)(&Asl[buf][c * 8]), 16, 0, 0);
        }
        #pragma unroll
        for (int q = 0; q < 2; ++q) {
            int c = q * 256 + tid;
            int row = c >> 3;
            int ksl = ((c & 7) ^ (row & 7)) << 3;
            __builtin_amdgcn_global_load_lds(
                (const __attribute__((address_space(1))) void*)(Bt + (size_t)(bn + row) * DIM + k0 + ksl),
                (__attribute__((address_space(3))) void*)(&Bsl[buf][c * 8]), 16, 0, 0);
        }
    };

    STAGE(0, 0);
    __syncthreads();                 // buf0 staged (syncthreads drains vmcnt)
    int cur = 0;
    for (int t = 0; t < DIM / 64; ++t) {
        if (t + 1 < DIM / 64) STAGE(cur ^ 1, (t + 1) * 64);   // issue next-tile loads
        #pragma unroll
        for (int kk = 0; kk < 2; ++kk) {
            const int sw = ((kk * 4 + kg) ^ (r & 7)) << 3;
            bf16x8 af[2], bfr[2];
            #pragma unroll
            for (int mi = 0; mi < 2; ++mi)
                af[mi] = *(const bf16x8*)&Asl[cur][(wm * 32 + mi * 16 + r) * 64 + sw];
            #pragma unroll
            for (int nj = 0; nj < 2; ++nj)
                bfr[nj] = *(const bf16x8*)&Bsl[cur][(wn * 32 + nj * 16 + r) * 64 + sw];
            #pragma unroll
            for (int mi = 0; mi < 2; ++mi)
                #pragma unroll
                for (int nj = 0; nj < 2; ++nj)
                    acc[mi][nj] = __builtin_amdgcn_mfma_f32_16x16x32_bf16(af[mi], bfr[nj], acc[mi][nj], 0, 0, 0);
        }
        __syncthreads();             // drains next-tile loads + everyone done reading cur
        cur ^= 1;
    }

    // epilogue: row = bm + wm*32 + mi*16 + kg*4 + j, col = bn + wn*32 + nj*16 + r
    #pragma unroll
    for (int nj = 0; nj < 2; ++nj) {
        const int col = bn + wn * 32 + nj * 16 + r;
        const float bv = bias[col];
        #pragma unroll
        for (int mi = 0; mi < 2; ++mi) {
            const int rowb = bm + wm * 32 + mi * 16 + kg * 4;
            #pragma unroll
            for (int j = 0; j < 4; ++j) {
                float v = acc[mi][nj][j] + bv;
                size_t idx = (size_t)(rowb + j) * DIM + col;
                if (ACT == 0) {
                    outb[idx] = to_bf16_bits(v);
                    outf[idx] = v / (1.f + __expf(-v));   // silu
                } else {
                    outf[idx] = softplus_f(v);
                }
            }
        }
    }
}

// ---------------- dbc = u @ W_x + b_x  (N=96, K=1024), 8 rows/block, K split in 2 ----------------
__global__ __launch_bounds__(256) void dbc_kernel(
    const float* __restrict__ u1, const float* __restrict__ u2,
    const float* __restrict__ Wx1, const float* __restrict__ bx1,
    const float* __restrict__ Wx2, const float* __restrict__ bx2,
    float* __restrict__ dbc1, float* __restrict__ dbc2) {
    const int s = blockIdx.y;
    const float* __restrict__ u   = s ? u2   : u1;
    const float* __restrict__ Wx  = s ? Wx2  : Wx1;
    const float* __restrict__ bx  = s ? bx2  : bx1;
    float* __restrict__ dbc       = s ? dbc2 : dbc1;
    const int row0 = blockIdx.x * 8;
    const int tid = threadIdx.x;
    const int kh = tid >> 7;       // 0,1 — K half
    const int j  = tid & 127;      // 0..127, active < 96
    __shared__ float part[8][96];
    float acc[8];
    if (j < 96) {
        const float bj = (kh == 0) ? bx[j] : 0.f;
        #pragma unroll
        for (int r = 0; r < 8; ++r) acc[r] = bj;
        const float* ur = u + (size_t)row0 * DIM + kh * 512;
        const float* wp = Wx + (size_t)(kh * 512) * 96 + j;
        for (int k = 0; k < 512; k += 4) {
            float4 uv[8];
            #pragma unroll
            for (int r = 0; r < 8; ++r) uv[r] = *(const float4*)(ur + (size_t)r * DIM + k);
            #pragma unroll
            for (int kk = 0; kk < 4; ++kk) {
                float w = wp[(size_t)(k + kk) * 96];
                #pragma unroll
                for (int r = 0; r < 8; ++r) {
                    float uvv = kk == 0 ? uv[r].x : kk == 1 ? uv[r].y : kk == 2 ? uv[r].z : uv[r].w;
                    acc[r] = fmaf(uvv, w, acc[r]);
                }
            }
        }
    }
    if (kh == 1 && j < 96) {
        #pragma unroll
        for (int r = 0; r < 8; ++r) part[r][j] = acc[r];
    }
    __syncthreads();
    if (kh == 0 && j < 96) {
        #pragma unroll
        for (int r = 0; r < 8; ++r)
            dbc[(size_t)(row0 + r) * 96 + j] = acc[r] + part[r][j];
    }
}

// ---------------- delta = softplus(dbc[:, :64] @ W_dt + b_dt) -> bf16 ----------------
__global__ __launch_bounds__(256) void delta_kernel(
    const float* __restrict__ dbc1, const float* __restrict__ dbc2,
    const float* __restrict__ Wdt1, const float* __restrict__ bdt1,
    const float* __restrict__ Wdt2, const float* __restrict__ bdt2,
    ushort_t* __restrict__ delta1, ushort_t* __restrict__ delta2) {
    const int s = blockIdx.y;
    const float* __restrict__ dbc = s ? dbc2 : dbc1;
    const float* __restrict__ Wdt = s ? Wdt2 : Wdt1;
    const float* __restrict__ bdt = s ? bdt2 : bdt1;
    ushort_t* __restrict__ delta  = s ? delta2 : delta1;
    const int row0 = blockIdx.x * 4;
    const int tid = threadIdx.x;
    __shared__ float rs[4][64];
    rs[tid >> 6][tid & 63] = dbc[(size_t)(row0 + (tid >> 6)) * 96 + (tid & 63)];
    __syncthreads();
    float acc[4][4];
    #pragma unroll
    for (int i = 0; i < 4; ++i) {
        float b = bdt[tid + 256 * i];
        #pragma unroll
        for (int r = 0; r < 4; ++r) acc[r][i] = b;
    }
    for (int k = 0; k < 64; ++k) {
        #pragma unroll
        for (int i = 0; i < 4; ++i) {
            float w = Wdt[(size_t)k * DIM + tid + 256 * i];
            #pragma unroll
            for (int r = 0; r < 4; ++r) acc[r][i] = fmaf(rs[r][k], w, acc[r][i]);
        }
    }
    #pragma unroll
    for (int r = 0; r < 4; ++r)
        #pragma unroll
        for (int i = 0; i < 4; ++i)
            delta[(size_t)(row0 + r) * DIM + tid + 256 * i] = to_bf16_bits(softplus_f(acc[r][i]));
}

// ---------------- chunked selective scan ----------------
// r/hin: [2][NB][NCH][DIM][DST] fp32 (4MB);  sδ: [2][NB][NCH][DIM] fp32 (0.25MB)
#define CH 4
#define SLOAD1(S, base) do { \
    _Pragma("unroll") for (int j_ = 0; j_ < CH; ++j_) { \
        const size_t rr_ = rowbase + (base) + j_; \
        dl##S[j_] = bf16_bits_to_f(delta[rr_ * DIM + d]); \
        uu##S[j_] = u[rr_ * DIM + d]; \
        Bn##S[j_] = dbc[rr_ * 96 + DTR + n]; \
    } \
} while (0)
#define SCOMP1(S) do { \
    _Pragma("unroll") for (int j_ = 0; j_ < CH; ++j_) { \
        float e_ = __expf(dl##S[j_] * a); \
        h = fmaf(e_, h, dl##S[j_] * Bn##S[j_] * uu##S[j_]); \
        sd += dl##S[j_]; \
    } \
} while (0)

__global__ __launch_bounds__(256) void scan_pass1(
    const ushort_t* __restrict__ delta1, const float* __restrict__ u1c, const float* __restrict__ dbc1,
    const float* __restrict__ Alog1,
    const ushort_t* __restrict__ delta2, const float* __restrict__ u2c, const float* __restrict__ dbc2,
    const float* __restrict__ Alog2,
    float* __restrict__ rbuf, float* __restrict__ sdbuf) {
    const int s = blockIdx.z;
    const ushort_t* __restrict__ delta = s ? delta2 : delta1;
    const float* __restrict__ u    = s ? u2c   : u1c;
    const float* __restrict__ dbc  = s ? dbc2  : dbc1;
    const float* __restrict__ Alog = s ? Alog2 : Alog1;
    const int tid = threadIdx.x;
    const int n = tid & 15;
    const int d = blockIdx.x * 16 + (tid >> 4);
    const int b = blockIdx.y >> 3;
    const int c = blockIdx.y & 7;
    const float a = -__expf(Alog[d * DST + n]);
    const size_t rowbase = (size_t)b * LSEQ + (size_t)c * TCH;
    float h = 0.f, sd = 0.f;
    float dlA[CH], uuA[CH], BnA[CH];
    float dlB[CH], uuB[CH], BnB[CH];
    SLOAD1(A, 0);
    for (int t = 0; t < TCH; t += 2 * CH) {
        SLOAD1(B, t + CH);
        SCOMP1(A);
        if (t + 2 * CH < TCH) SLOAD1(A, t + 2 * CH);
        SCOMP1(B);
    }
    const size_t ridx = ((((size_t)s * NB + b) * NCH + c) * DIM + d) * DST + n;
    rbuf[ridx] = h;
    if (n == 0) sdbuf[(((size_t)s * NB + b) * NCH + c) * DIM + d] = sd;
}

__global__ __launch_bounds__(256) void scan_combine(
    const float* __restrict__ Alog1, const float* __restrict__ Alog2,
    float* __restrict__ rbuf, const float* __restrict__ sdbuf) {
    const int tid = threadIdx.x;
    const int sb = blockIdx.x >> 6;         // 0..7
    const int s = sb >> 2, b = sb & 3;
    const int flat = (blockIdx.x & 63) * 256 + tid;
    const int d = flat >> 4, n = flat & 15;
    const float* Alog = s ? Alog2 : Alog1;
    const float a = -__expf(Alog[d * DST + n]);
    float hprev = 0.f;
    #pragma unroll
    for (int c = 0; c < NCH; ++c) {
        const size_t ridx = ((((size_t)s * NB + b) * NCH + c) * DIM + d) * DST + n;
        float rc = rbuf[ridx];
        float P = __expf(a * sdbuf[(((size_t)s * NB + b) * NCH + c) * DIM + d]);
        float hnew = fmaf(P, hprev, rc);
        rbuf[ridx] = hprev;                 // overwrite r_c with hin_c
        hprev = hnew;
    }
}

#define SLOAD2(S, base) do { \
    _Pragma("unroll") for (int j_ = 0; j_ < CH; ++j_) { \
        const size_t rr_ = rowbase + (base) + j_; \
        dl##S[j_] = bf16_bits_to_f(delta[rr_ * DIM + d]); \
        uu##S[j_] = u[rr_ * DIM + d]; \
        Bn##S[j_] = dbc[rr_ * 96 + DTR + n]; \
        Cn##S[j_] = dbc[rr_ * 96 + DTR + DST + n]; \
    } \
} while (0)
#define SCOMP2(S, base) do { \
    _Pragma("unroll") for (int j_ = 0; j_ < CH; ++j_) { \
        float e_ = __expf(dl##S[j_] * a); \
        h = fmaf(e_, h, dl##S[j_] * Bn##S[j_] * uu##S[j_]); \
        float p_ = h * Cn##S[j_]; \
        p_ = dpp_add<0xB1>(p_); \
        p_ = dpp_add<0x4E>(p_); \
        p_ = dpp_add<0x124>(p_); \
        p_ = dpp_add<0x128>(p_); \
        if (n == 0) y[(rowbase + (base) + j_) * DIM + d] = fmaf(uu##S[j_], dcf, p_); \
    } \
} while (0)

__global__ __launch_bounds__(256) void scan_pass2(
    const ushort_t* __restrict__ delta1, const float* __restrict__ u1c, const float* __restrict__ dbc1,
    const float* __restrict__ Alog1, const float* __restrict__ D1p, float* __restrict__ y1,
    const ushort_t* __restrict__ delta2, const float* __restrict__ u2c, const float* __restrict__ dbc2,
    const float* __restrict__ Alog2, const float* __restrict__ D2p, float* __restrict__ y2,
    const float* __restrict__ rbuf) {
    const int s = blockIdx.z;
    const ushort_t* __restrict__ delta = s ? delta2 : delta1;
    const float* __restrict__ u    = s ? u2c   : u1c;
    const float* __restrict__ dbc  = s ? dbc2  : dbc1;
    const float* __restrict__ Alog = s ? Alog2 : Alog1;
    const float* __restrict__ Dp   = s ? D2p   : D1p;
    float* __restrict__ y          = s ? y2    : y1;
    const int tid = threadIdx.x;
    const int n = tid & 15;
    const int d = blockIdx.x * 16 + (tid >> 4);
    const int b = blockIdx.y >> 3;
    const int c = blockIdx.y & 7;
    const float a = -__expf(Alog[d * DST + n]);
    const float dcf = Dp[d];
    const size_t rowbase = (size_t)b * LSEQ + (size_t)c * TCH;
    float h = rbuf[((((size_t)s * NB + b) * NCH + c) * DIM + d) * DST + n];  // hin
    float dlA[CH], uuA[CH], BnA[CH], CnA[CH];
    float dlB[CH], uuB[CH], BnB[CH], CnB[CH];
    SLOAD2(A, 0);
    for (int t = 0; t < TCH; t += 2 * CH) {
        SLOAD2(B, t + CH);
        SCOMP2(A, t);
        if (t + 2 * CH < TCH) SLOAD2(A, t + 2 * CH);
        SCOMP2(B, t + CH);
    }
}

// ---------------- out = (y1 + y2) * z + skip  (z lives in d_out) ----------------
__global__ __launch_bounds__(256) void final_kernel(
    const float* __restrict__ y1, const float* __restrict__ y2,
    const float* __restrict__ skip, float* io) {
    const int i = blockIdx.x * 256 + threadIdx.x;
    float4 a = ((const float4*)y1)[i];
    float4 b = ((const float4*)y2)[i];
    float4 sk = ((const float4*)skip)[i];
    float4 z = ((float4*)io)[i];
    float4 o;
    o.x = (a.x + b.x) * z.x + sk.x;
    o.y = (a.y + b.y) * z.y + sk.y;
    o.z = (a.z + b.z) * z.z + sk.z;
    o.w = (a.w + b.w) * z.w + sk.w;
    ((float4*)io)[i] = o;
}

extern "C" void kernel_launch(void* const* d_in, const int* in_sizes, int n_in,
                              void* d_out, int out_size, void* d_ws, size_t ws_size,
                              hipStream_t stream) {
    const float* inputs = (const float*)d_in[0];
    const float* gamma  = (const float*)d_in[1];
    const float* beta   = (const float*)d_in[2];
    const float* W_proj = (const float*)d_in[3];
    const float* b_proj = (const float*)d_in[4];
    const float* W_fc   = (const float*)d_in[5];
    const float* b_fc   = (const float*)d_in[6];
    const float* W_bc   = (const float*)d_in[7];
    const float* b_bc   = (const float*)d_in[8];
    const float* W_x1   = (const float*)d_in[9];
    const float* b_x1   = (const float*)d_in[10];
    const float* W_dt1  = (const float*)d_in[11];
    const float* b_dt1  = (const float*)d_in[12];
    const float* A_log1 = (const float*)d_in[13];
    const float* D1     = (const float*)d_in[14];
    const float* W_x2   = (const float*)d_in[15];
    const float* b_x2   = (const float*)d_in[16];
    const float* W_dt2  = (const float*)d_in[17];
    const float* b_dt2  = (const float*)d_in[18];
    const float* A_log2 = (const float*)d_in[19];
    const float* D2     = (const float*)d_in[20];
    float* out = (float*)d_out;
    char* wsb  = (char*)d_ws;

    // workspace layout (47.5 MB total):
    ushort_t* xln_bf  = (ushort_t*)wsb;                          // 4MB
    ushort_t* proj_bf = (ushort_t*)(wsb + (4u << 20));           // 4MB
    float*    y1      = (float*)wsb;                             // 8MB, overlays xln/proj (dead by scan)
    float*    u1      = (float*)(wsb + (8u << 20));              // 8MB
    float*    u2      = (float*)(wsb + (16u << 20));             // 8MB
    float*    y2      = (float*)(wsb + (24u << 20));             // 8MB
    ushort_t* delta1  = (ushort_t*)(wsb + (32u << 20));          // 4MB
    ushort_t* delta2  = (ushort_t*)(wsb + (36u << 20));          // 4MB
    ushort_t* WtP     = (ushort_t*)(wsb + (40u << 20));          // 2MB (dead by scan)
    ushort_t* WtF     = (ushort_t*)(wsb + (42u << 20));          // 2MB (dead by scan)
    ushort_t* WtB     = (ushort_t*)(wsb + (44u << 20));          // 2MB (dead by scan)
    float*    rbuf    = (float*)(wsb + (40u << 20));             // 4MB, overlays WtP/WtF
    float*    sdbuf   = (float*)(wsb + (44u << 20));             // 0.25MB, overlays WtB
    float*    dbc1    = (float*)(wsb + (46u << 20));             // 0.75MB
    float*    dbc2    = dbc1 + (size_t)NTOK * 96;                // 0.75MB
    float*    zbuf    = out;                                     // z = silu(proj) staged in d_out

    wconv_kernel<<<dim3(16, 16, 3), 256, 0, stream>>>(W_proj, W_fc, W_bc, WtP, WtF, WtB);
    ln_kernel<<<NTOK, 256, 0, stream>>>(inputs, gamma, beta, xln_bf);
    mfma_gemm<0><<<dim3(DIM / 64, NTOK / 64), 256, 0, stream>>>(xln_bf, WtP, b_proj, proj_bf, zbuf);
    mfma_gemm<1><<<dim3(DIM / 64, NTOK / 64), 256, 0, stream>>>(proj_bf, WtF, b_fc, nullptr, u1);
    mfma_gemm<1><<<dim3(DIM / 64, NTOK / 64), 256, 0, stream>>>(proj_bf, WtB, b_bc, nullptr, u2);
    dbc_kernel<<<dim3(NTOK / 8, 2), 256, 0, stream>>>(u1, u2, W_x1, b_x1, W_x2, b_x2, dbc1, dbc2);
    delta_kernel<<<dim3(NTOK / 4, 2), 256, 0, stream>>>(dbc1, dbc2, W_dt1, b_dt1, W_dt2, b_dt2, delta1, delta2);
    scan_pass1<<<dim3(DIM / 16, NB * NCH, 2), 256, 0, stream>>>(delta1, u1, dbc1, A_log1,
                                                                delta2, u2, dbc2, A_log2, rbuf, sdbuf);
    scan_combine<<<512, 256, 0, stream>>>(A_log1, A_log2, rbuf, sdbuf);
    scan_pass2<<<dim3(DIM / 16, NB * NCH, 2), 256, 0, stream>>>(delta1, u1, dbc1, A_log1, D1, y1,
                                                                delta2, u2, dbc2, A_log2, D2, y2, rbuf);
    final_kernel<<<(size_t)NTOK * DIM / 4 / 256, 256, 0, stream>>>(y1, y2, inputs, out);
}

// Round 6
// 313.719 us; speedup vs baseline: 1.8979x; 1.0774x over previous
//
#include <hip/hip_runtime.h>
#include <hip/hip_bf16.h>
#include <math.h>

#define DIM 1024
#define NTOK 2048   // B*L = 4*512
#define LSEQ 512
#define NB 4
#define DTR 64
#define DST 16
#define NCH 8
#define TCH 64      // LSEQ / NCH

typedef unsigned short ushort_t;
typedef __attribute__((ext_vector_type(8))) short bf16x8;
typedef __attribute__((ext_vector_type(4))) float f32x4;

__device__ __forceinline__ float softplus_f(float x) {
    return (x > 20.f) ? x : log1pf(__expf(x));
}
__device__ __forceinline__ ushort_t to_bf16_bits(float f) {
    __hip_bfloat16 h = __float2bfloat16(f);
    return *(ushort_t*)&h;
}
__device__ __forceinline__ float bf16_bits_to_f(ushort_t b) {
    return __uint_as_float(((unsigned int)b) << 16);
}
// x + dpp_perm(x); ctrl: 0xB1=quad xor1, 0x4E=quad xor2, 0x124=row_ror:4, 0x128=row_ror:8
template<int CTRL>
__device__ __forceinline__ float dpp_add(float x) {
    int xi = __float_as_int(x);
    int yi = __builtin_amdgcn_update_dpp(xi, xi, CTRL, 0xF, 0xF, false);
    return x + __int_as_float(yi);
}

// ---------------- weight transpose + bf16 convert: Wt[n][k] = bf16(W[k][n]) ----------------
__global__ __launch_bounds__(256) void wconv_kernel(
    const float* __restrict__ W0, const float* __restrict__ W1, const float* __restrict__ W2,
    ushort_t* __restrict__ T0, ushort_t* __restrict__ T1, ushort_t* __restrict__ T2) {
    const float* W = blockIdx.z == 0 ? W0 : blockIdx.z == 1 ? W1 : W2;
    ushort_t* T    = blockIdx.z == 0 ? T0 : blockIdx.z == 1 ? T1 : T2;
    __shared__ float tile[64][65];
    const int k0 = blockIdx.x * 64, n0 = blockIdx.y * 64;
    const int tid = threadIdx.x;
    #pragma unroll
    for (int p = 0; p < 16; ++p) {
        int idx = p * 256 + tid;
        int i = idx >> 6, j = idx & 63;
        tile[i][j] = W[(size_t)(k0 + i) * DIM + n0 + j];
    }
    __syncthreads();
    #pragma unroll
    for (int p = 0; p < 16; ++p) {
        int idx = p * 256 + tid;
        int j = idx >> 6, i = idx & 63;
        T[(size_t)(n0 + j) * DIM + k0 + i] = to_bf16_bits(tile[i][j]);
    }
}

// ---------------- LayerNorm -> bf16 ----------------
__global__ __launch_bounds__(256) void ln_kernel(
    const float* __restrict__ x, const float* __restrict__ gamma,
    const float* __restrict__ beta, ushort_t* __restrict__ out) {
    const int row = blockIdx.x;
    const int tid = threadIdx.x;
    const float4* xr = (const float4*)(x + (size_t)row * DIM);
    float4 v = xr[tid];
    float s  = v.x + v.y + v.z + v.w;
    float sq = v.x*v.x + v.y*v.y + v.z*v.z + v.w*v.w;
    for (int o = 32; o > 0; o >>= 1) {
        s  += __shfl_down(s, o);
        sq += __shfl_down(sq, o);
    }
    __shared__ float red[8];
    if ((tid & 63) == 0) { red[tid >> 6] = s; red[4 + (tid >> 6)] = sq; }
    __syncthreads();
    float st  = red[0] + red[1] + red[2] + red[3];
    float sqt = red[4] + red[5] + red[6] + red[7];
    float mu = st * (1.f / DIM);
    float var = sqt * (1.f / DIM) - mu * mu;
    float rstd = rsqrtf(var + 1e-6f);
    float4 g = ((const float4*)gamma)[tid];
    float4 bt = ((const float4*)beta)[tid];
    ushort4 ob;
    ob.x = to_bf16_bits((v.x - mu) * rstd * g.x + bt.x);
    ob.y = to_bf16_bits((v.y - mu) * rstd * g.y + bt.y);
    ob.z = to_bf16_bits((v.z - mu) * rstd * g.z + bt.z);
    ob.w = to_bf16_bits((v.w - mu) * rstd * g.w + bt.w);
    ((ushort4*)(out + (size_t)row * DIM))[tid] = ob;
}

// ---------------- bf16 MFMA GEMM, 64x64 tile, BK=64, double-buffered LDS ----------------
// 4 waves in 2x2; wave tile 32x32 = 2x2 frags of 16x16.
// LDS [row][k8slot*8], k8slot = k8 ^ (row&7); pre-swizzled global source (rule #21).
// ACT 0: outb = bf16(v), outf = silu(v).
// ACT 1: outf = softplus(v) fp32, outb = bf16(softplus(v)).
// ACT 2: outb = bf16(softplus(v)).
template<int ACT>
__global__ __launch_bounds__(256) void mfma_gemm(
    const ushort_t* __restrict__ A, const ushort_t* __restrict__ Bt,
    const float* __restrict__ bias, ushort_t* __restrict__ outb, float* __restrict__ outf) {
    __shared__ __align__(16) ushort_t Asl[2][64 * 64];
    __shared__ __align__(16) ushort_t Bsl[2][64 * 64];
    const int tid = threadIdx.x;
    const int bm = blockIdx.y * 64;
    const int bn = blockIdx.x * 64;
    const int lane = tid & 63;
    const int wid = tid >> 6;
    const int r  = lane & 15;
    const int kg = lane >> 4;            // 0..3
    const int wm = wid >> 1, wn = wid & 1;

    f32x4 acc[2][2] = {};

    auto STAGE = [&](int buf, int k0) {
        #pragma unroll
        for (int q = 0; q < 2; ++q) {
            int c = q * 256 + tid;
            int row = c >> 3;
            int ksl = ((c & 7) ^ (row & 7)) << 3;
            __builtin_amdgcn_global_load_lds(
                (const __attribute__((address_space(1))) void*)(A + (size_t)(bm + row) * DIM + k0 + ksl),
                (__attribute__((address_space(3))) void*)(&Asl[buf][c * 8]), 16, 0, 0);
        }
        #pragma unroll
        for (int q = 0; q < 2; ++q) {
            int c = q * 256 + tid;
            int row = c >> 3;
            int ksl = ((c & 7) ^ (row & 7)) << 3;
            __builtin_amdgcn_global_load_lds(
                (const __attribute__((address_space(1))) void*)(Bt + (size_t)(bn + row) * DIM + k0 + ksl),
                (__attribute__((address_space(3))) void*)(&Bsl[buf][c * 8]), 16, 0, 0);
        }
    };

    STAGE(0, 0);
    __syncthreads();                 // buf0 staged (syncthreads drains vmcnt)
    int cur = 0;
    for (int t = 0; t < DIM / 64; ++t) {
        if (t + 1 < DIM / 64) STAGE(cur ^ 1, (t + 1) * 64);   // issue next-tile loads
        #pragma unroll
        for (int kk = 0; kk < 2; ++kk) {
            const int sw = ((kk * 4 + kg) ^ (r & 7)) << 3;
            bf16x8 af[2], bfr[2];
            #pragma unroll
            for (int mi = 0; mi < 2; ++mi)
                af[mi] = *(const bf16x8*)&Asl[cur][(wm * 32 + mi * 16 + r) * 64 + sw];
            #pragma unroll
            for (int nj = 0; nj < 2; ++nj)
                bfr[nj] = *(const bf16x8*)&Bsl[cur][(wn * 32 + nj * 16 + r) * 64 + sw];
            #pragma unroll
            for (int mi = 0; mi < 2; ++mi)
                #pragma unroll
                for (int nj = 0; nj < 2; ++nj)
                    acc[mi][nj] = __builtin_amdgcn_mfma_f32_16x16x32_bf16(af[mi], bfr[nj], acc[mi][nj], 0, 0, 0);
        }
        __syncthreads();             // drains next-tile loads + everyone done reading cur
        cur ^= 1;
    }

    // epilogue: row = bm + wm*32 + mi*16 + kg*4 + j, col = bn + wn*32 + nj*16 + r
    #pragma unroll
    for (int nj = 0; nj < 2; ++nj) {
        const int col = bn + wn * 32 + nj * 16 + r;
        const float bv = bias[col];
        #pragma unroll
        for (int mi = 0; mi < 2; ++mi) {
            const int rowb = bm + wm * 32 + mi * 16 + kg * 4;
            #pragma unroll
            for (int j = 0; j < 4; ++j) {
                float v = acc[mi][nj][j] + bv;
                size_t idx = (size_t)(rowb + j) * DIM + col;
                if (ACT == 0) {
                    outb[idx] = to_bf16_bits(v);
                    outf[idx] = v / (1.f + __expf(-v));   // silu
                } else if (ACT == 1) {
                    float sp = softplus_f(v);
                    outf[idx] = sp;
                    outb[idx] = to_bf16_bits(sp);
                } else {
                    outb[idx] = to_bf16_bits(softplus_f(v));
                }
            }
        }
    }
}

// ---------------- Wcomb precompute ----------------
// WcombT[s][j][i] = bf16( sum_r W_x[i][r] * W_dt[r][j] ),  r < 64
// aux blocks (blockIdx.y==16): WxBCt[s][c][i] = bf16(W_x[i][64+c]) (c<32);
//                              bcomb[s][j] = b_dt[j] + sum_r b_x[r]*W_dt[r][j]
__global__ __launch_bounds__(256) void wcomb_kernel(
    const float* __restrict__ Wx1, const float* __restrict__ Wdt1,
    const float* __restrict__ bx1, const float* __restrict__ bdt1,
    const float* __restrict__ Wx2, const float* __restrict__ Wdt2,
    const float* __restrict__ bx2, const float* __restrict__ bdt2,
    ushort_t* __restrict__ WcombT, ushort_t* __restrict__ WxBCt,
    float* __restrict__ bcomb) {
    const int s = blockIdx.z;
    const float* __restrict__ Wx  = s ? Wx2  : Wx1;   // [1024][96]
    const float* __restrict__ Wdt = s ? Wdt2 : Wdt1;  // [64][1024]
    const float* __restrict__ bx  = s ? bx2  : bx1;
    const float* __restrict__ bdt = s ? bdt2 : bdt1;
    const int tid = threadIdx.x;
    __shared__ float Xs[64][65];   // [i][r]
    __shared__ float Ds[64][65];   // [r][j]
    if (blockIdx.y == 16) {
        // aux: transpose BC weights + bcomb for i/j-range blockIdx.x*64..+63
        const int i0 = blockIdx.x * 64;
        #pragma unroll
        for (int p = 0; p < 8; ++p) {
            int idx = p * 256 + tid;       // 0..2047 over [c=idx>>6][i=i0+(idx&63)]
            int c = idx >> 6, i = i0 + (idx & 63);
            WxBCt[((size_t)s * 32 + c) * DIM + i] = to_bf16_bits(Wx[(size_t)i * 96 + 64 + c]);
        }
        // bcomb for j in [i0, i0+64): threads 0..63
        if (tid < 64) {
            int j = i0 + tid;
            float acc = bdt[j];
            for (int r = 0; r < 64; ++r) acc = fmaf(bx[r], Wdt[(size_t)r * DIM + j], acc);
            bcomb[(size_t)s * DIM + j] = acc;
        }
        return;
    }
    const int i0 = blockIdx.x * 64, j0 = blockIdx.y * 64;
    #pragma unroll
    for (int p = 0; p < 16; ++p) {
        int idx = p * 256 + tid;
        int i = idx >> 6, r = idx & 63;
        Xs[i][r] = Wx[(size_t)(i0 + i) * 96 + r];
    }
    #pragma unroll
    for (int p = 0; p < 16; ++p) {
        int idx = p * 256 + tid;
        int r = idx >> 6, j = idx & 63;
        Ds[r][j] = Wdt[(size_t)r * DIM + j0 + j];
    }
    __syncthreads();
    const int tj = (tid >> 4) * 4, ti = (tid & 15) * 4;
    float acc[4][4] = {};
    for (int r = 0; r < 64; ++r) {
        float a[4], b[4];
        #pragma unroll
        for (int q = 0; q < 4; ++q) a[q] = Ds[r][tj + q];
        #pragma unroll
        for (int q = 0; q < 4; ++q) b[q] = Xs[ti + q][r];
        #pragma unroll
        for (int ji = 0; ji < 4; ++ji)
            #pragma unroll
            for (int ii = 0; ii < 4; ++ii)
                acc[ji][ii] = fmaf(a[ji], b[ii], acc[ji][ii]);
    }
    #pragma unroll
    for (int ji = 0; ji < 4; ++ji)
        #pragma unroll
        for (int ii = 0; ii < 4; ++ii)
            WcombT[((size_t)s * DIM + j0 + tj + ji) * DIM + i0 + ti + ii] = to_bf16_bits(acc[ji][ii]);
}

// ---------------- BC = u @ W_x[:,64:96] + b_x[64:96], split-K MFMA + atomics ----------------
// grid (NTOK/64, 4 k-chunks, 2 s); BC [2][NTOK][32] fp32, pre-zeroed.
__global__ __launch_bounds__(256) void bc_kernel(
    const ushort_t* __restrict__ u1b, const ushort_t* __restrict__ u2b,
    const ushort_t* __restrict__ WxBCt,
    const float* __restrict__ bx1, const float* __restrict__ bx2,
    float* __restrict__ BC) {
    const int s = blockIdx.z;
    const ushort_t* __restrict__ u  = s ? u2b : u1b;
    const ushort_t* __restrict__ Bt = WxBCt + (size_t)s * 32 * DIM;
    const float* __restrict__ bx    = s ? bx2 : bx1;
    const int bm = blockIdx.x * 64;
    const int kbase = blockIdx.y * 256;
    __shared__ __align__(16) ushort_t Asl[2][64 * 64];
    __shared__ __align__(16) ushort_t Bsl[2][32 * 64];
    const int tid = threadIdx.x;
    const int lane = tid & 63, wid = tid >> 6;
    const int r = lane & 15, kg = lane >> 4;
    f32x4 acc[2] = {};
    auto STAGE = [&](int buf, int k0) {
        #pragma unroll
        for (int q = 0; q < 2; ++q) {
            int c = q * 256 + tid;
            int row = c >> 3;
            int ksl = ((c & 7) ^ (row & 7)) << 3;
            __builtin_amdgcn_global_load_lds(
                (const __attribute__((address_space(1))) void*)(u + (size_t)(bm + row) * DIM + k0 + ksl),
                (__attribute__((address_space(3))) void*)(&Asl[buf][c * 8]), 16, 0, 0);
        }
        {
            int c = tid;
            int row = c >> 3;
            int ksl = ((c & 7) ^ (row & 7)) << 3;
            __builtin_amdgcn_global_load_lds(
                (const __attribute__((address_space(1))) void*)(Bt + (size_t)row * DIM + k0 + ksl),
                (__attribute__((address_space(3))) void*)(&Bsl[buf][c * 8]), 16, 0, 0);
        }
    };
    STAGE(0, kbase);
    __syncthreads();
    int cur = 0;
    for (int t = 0; t < 4; ++t) {
        if (t + 1 < 4) STAGE(cur ^ 1, kbase + (t + 1) * 64);
        #pragma unroll
        for (int kk = 0; kk < 2; ++kk) {
            const int sw = ((kk * 4 + kg) ^ (r & 7)) << 3;
            bf16x8 af = *(const bf16x8*)&Asl[cur][(wid * 16 + r) * 64 + sw];
            #pragma unroll
            for (int nj = 0; nj < 2; ++nj) {
                bf16x8 bfr = *(const bf16x8*)&Bsl[cur][(nj * 16 + r) * 64 + sw];
                acc[nj] = __builtin_amdgcn_mfma_f32_16x16x32_bf16(af, bfr, acc[nj], 0, 0, 0);
            }
        }
        __syncthreads();
        cur ^= 1;
    }
    const bool kc0 = (blockIdx.y == 0);
    #pragma unroll
    for (int nj = 0; nj < 2; ++nj) {
        const int col = nj * 16 + r;
        #pragma unroll
        for (int j = 0; j < 4; ++j) {
            const int row = bm + wid * 16 + kg * 4 + j;
            float v = acc[nj][j];
            if (kc0) v += bx[64 + col];
            atomicAdd(&BC[((size_t)s * NTOK + row) * 32 + col], v);
        }
    }
}

// ---------------- chunked selective scan ----------------
// rbuf: [2][NB][NCH][DIM][DST] fp32 (4MB);  sdbuf: [2][NB][NCH][DIM] fp32 (0.25MB)
#define CH 4
#define SLOAD1(S, base) do { \
    _Pragma("unroll") for (int j_ = 0; j_ < CH; ++j_) { \
        const size_t rr_ = rowbase + (base) + j_; \
        dl##S[j_] = bf16_bits_to_f(delta[rr_ * DIM + d]); \
        uu##S[j_] = u[rr_ * DIM + d]; \
        Bn##S[j_] = BCp[rr_ * 32 + n]; \
    } \
} while (0)
#define SCOMP1(S) do { \
    _Pragma("unroll") for (int j_ = 0; j_ < CH; ++j_) { \
        float e_ = __expf(dl##S[j_] * a); \
        h = fmaf(e_, h, dl##S[j_] * Bn##S[j_] * uu##S[j_]); \
        sd += dl##S[j_]; \
    } \
} while (0)

__global__ __launch_bounds__(256) void scan_pass1(
    const ushort_t* __restrict__ delta1, const float* __restrict__ u1c,
    const float* __restrict__ Alog1,
    const ushort_t* __restrict__ delta2, const float* __restrict__ u2c,
    const float* __restrict__ Alog2, const float* __restrict__ BC,
    float* __restrict__ rbuf, float* __restrict__ sdbuf) {
    const int s = blockIdx.z;
    const ushort_t* __restrict__ delta = s ? delta2 : delta1;
    const float* __restrict__ u    = s ? u2c   : u1c;
    const float* __restrict__ Alog = s ? Alog2 : Alog1;
    const float* __restrict__ BCp  = BC + (size_t)s * NTOK * 32;
    const int tid = threadIdx.x;
    const int n = tid & 15;
    const int d = blockIdx.x * 16 + (tid >> 4);
    const int b = blockIdx.y >> 3;
    const int c = blockIdx.y & 7;
    const float a = -__expf(Alog[d * DST + n]);
    const size_t rowbase = (size_t)b * LSEQ + (size_t)c * TCH;
    float h = 0.f, sd = 0.f;
    float dlA[CH], uuA[CH], BnA[CH];
    float dlB[CH], uuB[CH], BnB[CH];
    SLOAD1(A, 0);
    for (int t = 0; t < TCH; t += 2 * CH) {
        SLOAD1(B, t + CH);
        SCOMP1(A);
        if (t + 2 * CH < TCH) SLOAD1(A, t + 2 * CH);
        SCOMP1(B);
    }
    const size_t ridx = ((((size_t)s * NB + b) * NCH + c) * DIM + d) * DST + n;
    rbuf[ridx] = h;
    if (n == 0) sdbuf[(((size_t)s * NB + b) * NCH + c) * DIM + d] = sd;
}

__global__ __launch_bounds__(256) void scan_combine(
    const float* __restrict__ Alog1, const float* __restrict__ Alog2,
    float* __restrict__ rbuf, const float* __restrict__ sdbuf) {
    const int tid = threadIdx.x;
    const int sb = blockIdx.x >> 6;         // 0..7
    const int s = sb >> 2, b = sb & 3;
    const int flat = (blockIdx.x & 63) * 256 + tid;
    const int d = flat >> 4, n = flat & 15;
    const float* Alog = s ? Alog2 : Alog1;
    const float a = -__expf(Alog[d * DST + n]);
    float hprev = 0.f;
    #pragma unroll
    for (int c = 0; c < NCH; ++c) {
        const size_t ridx = ((((size_t)s * NB + b) * NCH + c) * DIM + d) * DST + n;
        float rc = rbuf[ridx];
        float P = __expf(a * sdbuf[(((size_t)s * NB + b) * NCH + c) * DIM + d]);
        float hnew = fmaf(P, hprev, rc);
        rbuf[ridx] = hprev;                 // overwrite r_c with hin_c
        hprev = hnew;
    }
}

#define SLOAD2(S, base) do { \
    _Pragma("unroll") for (int j_ = 0; j_ < CH; ++j_) { \
        const size_t rr_ = rowbase + (base) + j_; \
        dl##S[j_] = bf16_bits_to_f(delta[rr_ * DIM + d]); \
        uu##S[j_] = u[rr_ * DIM + d]; \
        Bn##S[j_] = BCp[rr_ * 32 + n]; \
        Cn##S[j_] = BCp[rr_ * 32 + 16 + n]; \
    } \
} while (0)
#define SCOMP2(S, base) do { \
    _Pragma("unroll") for (int j_ = 0; j_ < CH; ++j_) { \
        float e_ = __expf(dl##S[j_] * a); \
        h = fmaf(e_, h, dl##S[j_] * Bn##S[j_] * uu##S[j_]); \
        float p_ = h * Cn##S[j_]; \
        p_ = dpp_add<0xB1>(p_); \
        p_ = dpp_add<0x4E>(p_); \
        p_ = dpp_add<0x124>(p_); \
        p_ = dpp_add<0x128>(p_); \
        if (n == 0) y[(rowbase + (base) + j_) * DIM + d] = fmaf(uu##S[j_], dcf, p_); \
    } \
} while (0)

__global__ __launch_bounds__(256) void scan_pass2(
    const ushort_t* __restrict__ delta1, const float* __restrict__ u1c,
    const float* __restrict__ Alog1, const float* __restrict__ D1p, float* __restrict__ y1,
    const ushort_t* __restrict__ delta2, const float* __restrict__ u2c,
    const float* __restrict__ Alog2, const float* __restrict__ D2p, float* __restrict__ y2,
    const float* __restrict__ BC, const float* __restrict__ rbuf) {
    const int s = blockIdx.z;
    const ushort_t* __restrict__ delta = s ? delta2 : delta1;
    const float* __restrict__ u    = s ? u2c   : u1c;
    const float* __restrict__ Alog = s ? Alog2 : Alog1;
    const float* __restrict__ Dp   = s ? D2p   : D1p;
    float* __restrict__ y          = s ? y2    : y1;
    const float* __restrict__ BCp  = BC + (size_t)s * NTOK * 32;
    const int tid = threadIdx.x;
    const int n = tid & 15;
    const int d = blockIdx.x * 16 + (tid >> 4);
    const int b = blockIdx.y >> 3;
    const int c = blockIdx.y & 7;
    const float a = -__expf(Alog[d * DST + n]);
    const float dcf = Dp[d];
    const size_t rowbase = (size_t)b * LSEQ + (size_t)c * TCH;
    float h = rbuf[((((size_t)s * NB + b) * NCH + c) * DIM + d) * DST + n];  // hin
    float dlA[CH], uuA[CH], BnA[CH], CnA[CH];
    float dlB[CH], uuB[CH], BnB[CH], CnB[CH];
    SLOAD2(A, 0);
    for (int t = 0; t < TCH; t += 2 * CH) {
        SLOAD2(B, t + CH);
        SCOMP2(A, t);
        if (t + 2 * CH < TCH) SLOAD2(A, t + 2 * CH);
        SCOMP2(B, t + CH);
    }
}

// ---------------- out = (y1 + y2) * z + skip  (z lives in d_out) ----------------
__global__ __launch_bounds__(256) void final_kernel(
    const float* __restrict__ y1, const float* __restrict__ y2,
    const float* __restrict__ skip, float* io) {
    const int i = blockIdx.x * 256 + threadIdx.x;
    float4 a = ((const float4*)y1)[i];
    float4 b = ((const float4*)y2)[i];
    float4 sk = ((const float4*)skip)[i];
    float4 z = ((float4*)io)[i];
    float4 o;
    o.x = (a.x + b.x) * z.x + sk.x;
    o.y = (a.y + b.y) * z.y + sk.y;
    o.z = (a.z + b.z) * z.z + sk.z;
    o.w = (a.w + b.w) * z.w + sk.w;
    ((float4*)io)[i] = o;
}

extern "C" void kernel_launch(void* const* d_in, const int* in_sizes, int n_in,
                              void* d_out, int out_size, void* d_ws, size_t ws_size,
                              hipStream_t stream) {
    const float* inputs = (const float*)d_in[0];
    const float* gamma  = (const float*)d_in[1];
    const float* beta   = (const float*)d_in[2];
    const float* W_proj = (const float*)d_in[3];
    const float* b_proj = (const float*)d_in[4];
    const float* W_fc   = (const float*)d_in[5];
    const float* b_fc   = (const float*)d_in[6];
    const float* W_bc   = (const float*)d_in[7];
    const float* b_bc   = (const float*)d_in[8];
    const float* W_x1   = (const float*)d_in[9];
    const float* b_x1   = (const float*)d_in[10];
    const float* W_dt1  = (const float*)d_in[11];
    const float* b_dt1  = (const float*)d_in[12];
    const float* A_log1 = (const float*)d_in[13];
    const float* D1     = (const float*)d_in[14];
    const float* W_x2   = (const float*)d_in[15];
    const float* b_x2   = (const float*)d_in[16];
    const float* W_dt2  = (const float*)d_in[17];
    const float* b_dt2  = (const float*)d_in[18];
    const float* A_log2 = (const float*)d_in[19];
    const float* D2     = (const float*)d_in[20];
    float* out = (float*)d_out;
    char* wsb  = (char*)d_ws;

    // workspace layout (46.75 MB peak), liveness-overlaid:
    ushort_t* xln_bf  = (ushort_t*)wsb;                          // 0-4MB
    ushort_t* proj_bf = (ushort_t*)(wsb + (4u << 20));           // 4-8MB
    float*    y1      = (float*)wsb;                             // 0-8MB (pass2; xln/proj dead)
    float*    u1      = (float*)(wsb + (8u << 20));              // 8-16MB
    float*    u2      = (float*)(wsb + (16u << 20));             // 16-24MB
    ushort_t* u1b     = (ushort_t*)(wsb + (24u << 20));          // 24-28MB (dead after delta GEMMs)
    ushort_t* u2b     = (ushort_t*)(wsb + (28u << 20));          // 28-32MB
    float*    y2      = (float*)(wsb + (24u << 20));             // 24-32MB (pass2; u*b dead)
    ushort_t* delta1  = (ushort_t*)(wsb + (32u << 20));          // 32-36MB
    ushort_t* delta2  = (ushort_t*)(wsb + (36u << 20));          // 36-40MB
    ushort_t* WtP     = (ushort_t*)(wsb + (40u << 20));          // 40-42MB (dead after proj GEMM)
    ushort_t* WtF     = (ushort_t*)(wsb + (42u << 20));          // 42-44MB (dead after u1 GEMM)
    ushort_t* WtB     = (ushort_t*)(wsb + (44u << 20));          // 44-46MB (dead after u2 GEMM)
    ushort_t* WxBCt   = (ushort_t*)(wsb + (40u << 20));          // 128KB (overlays WtP)
    float*    bcomb   = (float*)(wsb + (41u << 20));             // 8KB
    ushort_t* WcombT  = (ushort_t*)(wsb + (42u << 20));          // 4MB (overlays WtF/WtB)
    float*    rbuf    = (float*)(wsb + (42u << 20));             // 4MB (overlays WcombT after deltas)
    float*    BC      = (float*)(wsb + (46u << 20));             // 512KB [2][NTOK][32]
    float*    sdbuf   = (float*)(wsb + (46u << 20) + (512u << 10)); // 256KB
    float*    zbuf    = out;                                     // z = silu(proj) staged in d_out

    wconv_kernel<<<dim3(16, 16, 3), 256, 0, stream>>>(W_proj, W_fc, W_bc, WtP, WtF, WtB);
    ln_kernel<<<NTOK, 256, 0, stream>>>(inputs, gamma, beta, xln_bf);
    mfma_gemm<0><<<dim3(DIM / 64, NTOK / 64), 256, 0, stream>>>(xln_bf, WtP, b_proj, proj_bf, zbuf);
    mfma_gemm<1><<<dim3(DIM / 64, NTOK / 64), 256, 0, stream>>>(proj_bf, WtF, b_fc, u1b, u1);
    mfma_gemm<1><<<dim3(DIM / 64, NTOK / 64), 256, 0, stream>>>(proj_bf, WtB, b_bc, u2b, u2);
    wcomb_kernel<<<dim3(16, 17, 2), 256, 0, stream>>>(W_x1, W_dt1, b_x1, b_dt1,
                                                      W_x2, W_dt2, b_x2, b_dt2,
                                                      WcombT, WxBCt, bcomb);
    hipMemsetAsync(BC, 0, (size_t)2 * NTOK * 32 * sizeof(float), stream);
    bc_kernel<<<dim3(NTOK / 64, 4, 2), 256, 0, stream>>>(u1b, u2b, WxBCt, b_x1, b_x2, BC);
    mfma_gemm<2><<<dim3(DIM / 64, NTOK / 64), 256, 0, stream>>>(u1b, WcombT, bcomb, delta1, nullptr);
    mfma_gemm<2><<<dim3(DIM / 64, NTOK / 64), 256, 0, stream>>>(u2b, WcombT + (size_t)DIM * DIM,
                                                                bcomb + DIM, delta2, nullptr);
    scan_pass1<<<dim3(DIM / 16, NB * NCH, 2), 256, 0, stream>>>(delta1, u1, A_log1,
                                                                delta2, u2, A_log2, BC, rbuf, sdbuf);
    scan_combine<<<512, 256, 0, stream>>>(A_log1, A_log2, rbuf, sdbuf);
    scan_pass2<<<dim3(DIM / 16, NB * NCH, 2), 256, 0, stream>>>(delta1, u1, A_log1, D1, y1,
                                                                delta2, u2, A_log2, D2, y2, BC, rbuf);
    final_kernel<<<(size_t)NTOK * DIM / 4 / 256, 256, 0, stream>>>(y1, y2, inputs, out);
}